// Round 14
// baseline (738.393 us; speedup 1.0000x reference)
//
#include <hip/hip_runtime.h>
#include <hip/hip_bf16.h>

typedef __hip_bfloat16 bf16;
typedef __attribute__((ext_vector_type(8))) short bf16x8;
typedef __attribute__((ext_vector_type(4))) float f32x4;

#define N_NODES 100000
#define N_EDGES 1600000
#define IN_F    128
#define HH      3      // heads
#define DD      16     // out feats per head
#define HD      48     // HH*DD
#define NEG_SLOPE 0.2f
#define EPS_V   1e-9f

#define NB      391    // ceil(N_NODES / 256) buckets
#define BW_SH   8      // bucket = node >> 8 (256 nodes per bucket)
#define MS_T    8192   // edges per multisplit workgroup

__device__ __forceinline__ float leaky(float x) { return x >= 0.f ? x : NEG_SLOPE * x; }
__device__ __forceinline__ float b2f(bf16 x) { return __bfloat162float(x); }
__device__ __forceinline__ unsigned short bfbits(float x) {
    return __builtin_bit_cast(unsigned short, __float2bfloat16(x));
}
__device__ __forceinline__ unsigned pkbf(float a, float b) {
    return (unsigned)bfbits(a) | ((unsigned)bfbits(b) << 16);
}
__device__ __forceinline__ float ulo(unsigned u) { return __uint_as_float(u << 16); }
__device__ __forceinline__ float uhi(unsigned u) { return __uint_as_float(u & 0xffff0000u); }

// ------- GEMM via MFMA: 64 rows/block (4 waves x 16-row tile), bf16 LDS staging -------
#define FS_LD 136   // padded row length in bf16 elems
__global__ __launch_bounds__(256) void k_gemm(const float* __restrict__ feat,
                                              const float* __restrict__ W,
                                              bf16* __restrict__ ft16) {
    __shared__ unsigned short Fs[64][FS_LD];   // ~17.4 KB
    int t = threadIdx.x;
    int row0 = blockIdx.x * 64;
    int lane = t & 63, wv = t >> 6;

    int bc = lane & 15, bk0 = (lane >> 4) * 8;
    bf16x8 bfrag[4][3];
#pragma unroll
    for (int kk = 0; kk < 4; ++kk)
#pragma unroll
        for (int nt = 0; nt < 3; ++nt)
#pragma unroll
            for (int j = 0; j < 8; ++j)
                bfrag[kk][nt][j] =
                    (short)bfbits(W[(kk * 32 + bk0 + j) * HD + nt * 16 + bc]);

    for (int i = t; i < 64 * 32; i += 256) {
        int r = i >> 5, c4 = i & 31;
        int gr = row0 + r;
        float4 v = make_float4(0.f, 0.f, 0.f, 0.f);
        if (gr < N_NODES) v = ((const float4*)feat)[(size_t)gr * 32 + c4];
        *(uint2*)&Fs[r][c4 * 4] = make_uint2(pkbf(v.x, v.y), pkbf(v.z, v.w));
    }
    __syncthreads();

    int ar = lane & 15, ak0 = (lane >> 4) * 8;
    const unsigned short* arow = &Fs[wv * 16 + ar][0];
    f32x4 acc0 = {0.f, 0.f, 0.f, 0.f};
    f32x4 acc1 = {0.f, 0.f, 0.f, 0.f};
    f32x4 acc2 = {0.f, 0.f, 0.f, 0.f};
#pragma unroll
    for (int kk = 0; kk < 4; ++kk) {
        bf16x8 af = *(const bf16x8*)&arow[kk * 32 + ak0];
        acc0 = __builtin_amdgcn_mfma_f32_16x16x32_bf16(af, bfrag[kk][0], acc0, 0, 0, 0);
        acc1 = __builtin_amdgcn_mfma_f32_16x16x32_bf16(af, bfrag[kk][1], acc1, 0, 0, 0);
        acc2 = __builtin_amdgcn_mfma_f32_16x16x32_bf16(af, bfrag[kk][2], acc2, 0, 0, 0);
    }
    int orow = row0 + wv * 16 + (lane >> 4) * 4;
    int ocol = lane & 15;
#pragma unroll
    for (int r = 0; r < 4; ++r) {
        int gr = orow + r;
        if (gr < N_NODES) {
            bf16* o = ft16 + (size_t)gr * HD + ocol;
            o[0]  = __float2bfloat16(acc0[r]);
            o[16] = __float2bfloat16(acc1[r]);
            o[32] = __float2bfloat16(acc2[r]);
        }
    }
}

// ---------------- el/er from bf16 ft ----------------
__global__ void k_eler(const bf16* __restrict__ ft16, const float* __restrict__ attn_l,
                       const float* __restrict__ attn_r, float* __restrict__ el,
                       float* __restrict__ er) {
    int i = blockIdx.x * blockDim.x + threadIdx.x;  // n*3+h
    if (i >= N_NODES * HH) return;
    int h = i % HH;
    const uint4* p = (const uint4*)(ft16 + (size_t)i * DD);
    uint4 q0 = p[0], q1 = p[1];
    float x[DD];
    x[0] = ulo(q0.x);  x[1] = uhi(q0.x);  x[2] = ulo(q0.y);  x[3] = uhi(q0.y);
    x[4] = ulo(q0.z);  x[5] = uhi(q0.z);  x[6] = ulo(q0.w);  x[7] = uhi(q0.w);
    x[8] = ulo(q1.x);  x[9] = uhi(q1.x);  x[10] = ulo(q1.y); x[11] = uhi(q1.y);
    x[12] = ulo(q1.z); x[13] = uhi(q1.z); x[14] = ulo(q1.w); x[15] = uhi(q1.w);
    float sl = 0.f, sr = 0.f;
#pragma unroll
    for (int d = 0; d < DD; ++d) {
        sl += x[d] * attn_l[h * DD + d];
        sr += x[d] * attn_r[h * DD + d];
    }
    el[i] = sl;
    er[i] = sr;
}

// ---------------- K1: per-bucket histograms (LDS-privatized, int4 loads) -------------
__global__ __launch_bounds__(256) void k_bhist(const int4* __restrict__ src4,
                                               const int4* __restrict__ dst4,
                                               int* __restrict__ bcnt_s,
                                               int* __restrict__ bcnt_d) {
    __shared__ int ls[NB], ld_[NB];
    int t = threadIdx.x;
    for (int i = t; i < NB; i += 256) { ls[i] = 0; ld_[i] = 0; }
    __syncthreads();
    const int NE4 = N_EDGES / 4;
    for (int e = blockIdx.x * 256 + t; e < NE4; e += gridDim.x * 256) {
        int4 d = dst4[e];
        atomicAdd(&ld_[d.x >> BW_SH], 1);
        atomicAdd(&ld_[d.y >> BW_SH], 1);
        atomicAdd(&ld_[d.z >> BW_SH], 1);
        atomicAdd(&ld_[d.w >> BW_SH], 1);
        int4 s = src4[e];
        atomicAdd(&ls[s.x >> BW_SH], 1);
        atomicAdd(&ls[s.y >> BW_SH], 1);
        atomicAdd(&ls[s.z >> BW_SH], 1);
        atomicAdd(&ls[s.w >> BW_SH], 1);
    }
    __syncthreads();
    for (int i = t; i < NB; i += 256) {
        if (ld_[i]) atomicAdd(&bcnt_d[i], ld_[i]);
        if (ls[i]) atomicAdd(&bcnt_s[i], ls[i]);
    }
}

// ---------------- K2: scan bucket counts -> bucket bases (+ sentinels) -------------
__global__ __launch_bounds__(512) void k_bscan(const int* __restrict__ bcnt_d,
                                               int* __restrict__ bbase_d,
                                               const int* __restrict__ bcnt_s,
                                               int* __restrict__ bbase_s,
                                               int* __restrict__ rows_d,
                                               int* __restrict__ rows_s) {
    __shared__ int buf[512];
    const int* c = blockIdx.x ? bcnt_s : bcnt_d;
    int* o = blockIdx.x ? bbase_s : bbase_d;
    int t = threadIdx.x;
    int v = (t < NB) ? c[t] : 0;
    buf[t] = v;
    __syncthreads();
    for (int off = 1; off < 512; off <<= 1) {
        int u = (t >= off) ? buf[t - off] : 0;
        __syncthreads();
        buf[t] += u;
        __syncthreads();
    }
    if (t < NB) o[t] = buf[t] - v;      // exclusive
    if (t == NB - 1) o[NB] = buf[t];    // == N_EDGES
    if (t == 0) {
        if (blockIdx.x) rows_s[N_NODES] = N_EDGES;
        else            rows_d[N_NODES] = N_EDGES;
    }
}

// ---------------- K3: multisplit — bucket edges for both directions ----------------
__global__ __launch_bounds__(256) void k_msplit(const int* __restrict__ src,
                                                const int* __restrict__ dst,
                                                const int* __restrict__ bbase_d,
                                                const int* __restrict__ bbase_s,
                                                int* __restrict__ bfill_d,
                                                int* __restrict__ bfill_s,
                                                unsigned* __restrict__ bkt_d,
                                                unsigned* __restrict__ bkt_s) {
    __shared__ int lcD[NB], lcS[NB], wbD[NB], wbS[NB], rkD[NB], rkS[NB];
    int t = threadIdx.x;
    int e0 = blockIdx.x * MS_T;
    int e1 = min(e0 + MS_T, N_EDGES);
    for (int i = t; i < NB; i += 256) { lcD[i] = 0; lcS[i] = 0; rkD[i] = 0; rkS[i] = 0; }
    __syncthreads();
    for (int e = e0 + t; e < e1; e += 256) {
        atomicAdd(&lcD[dst[e] >> BW_SH], 1);
        atomicAdd(&lcS[src[e] >> BW_SH], 1);
    }
    __syncthreads();
    for (int i = t; i < NB; i += 256) {
        wbD[i] = bbase_d[i] + (lcD[i] ? atomicAdd(&bfill_d[i], lcD[i]) : 0);
        wbS[i] = bbase_s[i] + (lcS[i] ? atomicAdd(&bfill_s[i], lcS[i]) : 0);
    }
    __syncthreads();
    for (int e = e0 + t; e < e1; e += 256) {
        int s = src[e], d = dst[e];
        int bd = d >> BW_SH, bs = s >> BW_SH;
        int rd = atomicAdd(&rkD[bd], 1);
        int rs = atomicAdd(&rkS[bs], 1);
        bkt_d[wbD[bd] + rd] = (unsigned)s | ((unsigned)(d & 255) << 17);
        bkt_s[wbS[bs] + rs] = (unsigned)d | ((unsigned)(s & 255) << 17);
    }
}

// ------- K4: per-bucket CSR finalize, both directions in one launch (grid 2*NB) ------
__global__ __launch_bounds__(256) void k_bfinal2(const unsigned* __restrict__ bkt_d,
                                                 const unsigned* __restrict__ bkt_s,
                                                 const int* __restrict__ bbase_d,
                                                 const int* __restrict__ bbase_s,
                                                 int* __restrict__ rows_d,
                                                 int* __restrict__ rows_s,
                                                 int* __restrict__ srcs_d,
                                                 int* __restrict__ dsts_s) {
    __shared__ int cnt[256], pre[256], rnk[256], wsum[4];
    int bb = blockIdx.x, t = threadIdx.x;
    bool isD = bb < NB;
    int b = isD ? bb : bb - NB;
    const unsigned* bkt = isD ? bkt_d : bkt_s;
    const int* bbase = isD ? bbase_d : bbase_s;
    int* rows = isD ? rows_d : rows_s;
    int* outarr = isD ? srcs_d : dsts_s;
    int base = bbase[b], end = bbase[b + 1];
    cnt[t] = 0; rnk[t] = 0;
    __syncthreads();
    for (int i = base + t; i < end; i += 256)
        atomicAdd(&cnt[(bkt[i] >> 17) & 255], 1);
    __syncthreads();
    int lane = t & 63, w = t >> 6;
    int v = cnt[t];
    int sc = v;
#pragma unroll
    for (int off = 1; off < 64; off <<= 1) {
        int u = __shfl_up(sc, off, 64);
        if (lane >= off) sc += u;
    }
    if (lane == 63) wsum[w] = sc;
    __syncthreads();
    int wpre = 0;
    for (int j = 0; j < w; ++j) wpre += wsum[j];
    int excl = wpre + sc - v;
    pre[t] = excl;
    int n = (b << BW_SH) + t;
    if (n < N_NODES) rows[n] = base + excl;
    __syncthreads();
    for (int i = base + t; i < end; i += 256) {
        unsigned u = bkt[i];
        int loc = (u >> 17) & 255;
        int r = atomicAdd(&rnk[loc], 1);
        outarr[base + pre[loc] + r] = (int)(u & 0x1FFFFu);
    }
}

// -------- src-side segment softmax stats: per-node (max, sum) only ----------
__global__ __launch_bounds__(256) void k_seg_src(const int* __restrict__ dsts_s,
                                                 const int* __restrict__ rows_s,
                                                 const float* __restrict__ el,
                                                 const float* __restrict__ er,
                                                 float2* __restrict__ mssrc) {
    int wid = threadIdx.x >> 6, lane = threadIdx.x & 63;
    int n = blockIdx.x * 4 + wid;
    if (n >= N_NODES) return;
    int rs = rows_s[n], re = rows_s[n + 1];
    if (rs >= re) return;
    float el0 = el[n * 3 + 0], el1 = el[n * 3 + 1], el2 = el[n * 3 + 2];
    bool single = (re - rs) <= 64;
    float m0 = -INFINITY, m1 = -INFINITY, m2 = -INFINITY;
    float c0 = -INFINITY, c1 = -INFINITY, c2 = -INFINITY;
    for (int p0 = rs; p0 < re; p0 += 64) {
        int p = p0 + lane;
        bool act = p < re;
        int d = act ? dsts_s[p] : 0;
        float t0 = act ? leaky(el0 + er[d * 3 + 0]) : -INFINITY;
        float t1 = act ? leaky(el1 + er[d * 3 + 1]) : -INFINITY;
        float t2 = act ? leaky(el2 + er[d * 3 + 2]) : -INFINITY;
        if (single) { c0 = t0; c1 = t1; c2 = t2; }
        m0 = fmaxf(m0, t0); m1 = fmaxf(m1, t1); m2 = fmaxf(m2, t2);
    }
#pragma unroll
    for (int off = 1; off < 64; off <<= 1) {
        m0 = fmaxf(m0, __shfl_xor(m0, off));
        m1 = fmaxf(m1, __shfl_xor(m1, off));
        m2 = fmaxf(m2, __shfl_xor(m2, off));
    }
    float s0 = 0, s1 = 0, s2 = 0;
    if (single) {
        bool act = (rs + lane) < re;
        s0 = act ? expf(c0 - m0) : 0.f;
        s1 = act ? expf(c1 - m1) : 0.f;
        s2 = act ? expf(c2 - m2) : 0.f;
    } else {
        for (int p0 = rs; p0 < re; p0 += 64) {
            int p = p0 + lane;
            if (p < re) {
                int d = dsts_s[p];
                s0 += expf(leaky(el0 + er[d * 3 + 0]) - m0);
                s1 += expf(leaky(el1 + er[d * 3 + 1]) - m1);
                s2 += expf(leaky(el2 + er[d * 3 + 2]) - m2);
            }
        }
    }
#pragma unroll
    for (int off = 1; off < 64; off <<= 1) {
        s0 += __shfl_xor(s0, off);
        s1 += __shfl_xor(s1, off);
        s2 += __shfl_xor(s2, off);
    }
    if (lane == 0) {
        mssrc[n * 3 + 0] = make_float2(m0, s0);
        mssrc[n * 3 + 1] = make_float2(m1, s1);
        mssrc[n * 3 + 2] = make_float2(m2, s2);
    }
}

// ---- dst-side stats + fused symmetric attention; a stored bf16 [E][4] (pad=0) ----
__global__ __launch_bounds__(256) void k_seg_dst_attn(const int* __restrict__ srcs_d,
                                                      const int* __restrict__ rows_d,
                                                      const float* __restrict__ el,
                                                      const float* __restrict__ er,
                                                      const float2* __restrict__ mssrc,
                                                      ushort4* __restrict__ a16) {
    int wid = threadIdx.x >> 6, lane = threadIdx.x & 63;
    int n = blockIdx.x * 4 + wid;
    if (n >= N_NODES) return;
    int rs = rows_d[n], re = rows_d[n + 1];
    if (rs >= re) return;
    float er0 = er[n * 3 + 0], er1 = er[n * 3 + 1], er2 = er[n * 3 + 2];
    bool single = (re - rs) <= 64;
    float m0 = -INFINITY, m1 = -INFINITY, m2 = -INFINITY;
    float c0 = -INFINITY, c1 = -INFINITY, c2 = -INFINITY;
    int scache = 0;
    for (int p0 = rs; p0 < re; p0 += 64) {
        int p = p0 + lane;
        bool act = p < re;
        int s = act ? srcs_d[p] : 0;
        if (single) scache = s;
        float t0 = act ? leaky(el[s * 3 + 0] + er0) : -INFINITY;
        float t1 = act ? leaky(el[s * 3 + 1] + er1) : -INFINITY;
        float t2 = act ? leaky(el[s * 3 + 2] + er2) : -INFINITY;
        if (single) { c0 = t0; c1 = t1; c2 = t2; }
        m0 = fmaxf(m0, t0); m1 = fmaxf(m1, t1); m2 = fmaxf(m2, t2);
    }
#pragma unroll
    for (int off = 1; off < 64; off <<= 1) {
        m0 = fmaxf(m0, __shfl_xor(m0, off));
        m1 = fmaxf(m1, __shfl_xor(m1, off));
        m2 = fmaxf(m2, __shfl_xor(m2, off));
    }
    float s0 = 0, s1 = 0, s2 = 0;
    if (single) {
        bool act = (rs + lane) < re;
        s0 = act ? expf(c0 - m0) : 0.f;
        s1 = act ? expf(c1 - m1) : 0.f;
        s2 = act ? expf(c2 - m2) : 0.f;
    } else {
        for (int p0 = rs; p0 < re; p0 += 64) {
            int p = p0 + lane;
            if (p < re) {
                int s = srcs_d[p];
                s0 += expf(leaky(el[s * 3 + 0] + er0) - m0);
                s1 += expf(leaky(el[s * 3 + 1] + er1) - m1);
                s2 += expf(leaky(el[s * 3 + 2] + er2) - m2);
            }
        }
    }
#pragma unroll
    for (int off = 1; off < 64; off <<= 1) {
        s0 += __shfl_xor(s0, off);
        s1 += __shfl_xor(s1, off);
        s2 += __shfl_xor(s2, off);
    }
    float i0 = 1.f / s0, i1 = 1.f / s1, i2 = 1.f / s2;
    for (int p0 = rs; p0 < re; p0 += 64) {
        int p = p0 + lane;
        if (p >= re) break;
        int s = single ? scache : srcs_d[p];
        float t0, t1, t2;
        if (single) { t0 = c0; t1 = c1; t2 = c2; }
        else {
            t0 = leaky(el[s * 3 + 0] + er0);
            t1 = leaky(el[s * 3 + 1] + er1);
            t2 = leaky(el[s * 3 + 2] + er2);
        }
        float2 a0 = mssrc[s * 3 + 0], a1 = mssrc[s * 3 + 1], a2 = mssrc[s * 3 + 2];
        float d0 = fmaxf(expf(t0 - m0) * i0, EPS_V);
        float d1 = fmaxf(expf(t1 - m1) * i1, EPS_V);
        float d2 = fmaxf(expf(t2 - m2) * i2, EPS_V);
        float u0 = fmaxf(expf(t0 - a0.x) / a0.y, EPS_V);
        float u1 = fmaxf(expf(t1 - a1.x) / a1.y, EPS_V);
        float u2 = fmaxf(expf(t2 - a2.x) / a2.y, EPS_V);
        ushort4 w;
        w.x = bfbits(sqrtf(d0 * u0));
        w.y = bfbits(sqrtf(d1 * u1));
        w.z = bfbits(sqrtf(d2 * u2));
        w.w = 0;
        a16[p] = w;
    }
}

// ---- hop: wave per node, 48 lanes, 96 B bf16 rows, bf16 a [E][4], 16-deep pipeline ----
__global__ __launch_bounds__(256) void k_hop(const bf16* __restrict__ cur,
                                             const unsigned short* __restrict__ a16,
                                             const int* __restrict__ rows_d,
                                             const int* __restrict__ srcs_d,
                                             bf16* __restrict__ out) {
    int wid = threadIdx.x >> 6, lane = threadIdx.x & 63;
    int n = blockIdx.x * 4 + wid;
    if (n >= N_NODES) return;
    if (lane >= HD) return;
    int h = lane >> 4;
    int rs = rows_d[n], re = rows_d[n + 1];
    float acc = 0.f;
    int p = rs;
    for (; p + 16 <= re; p += 16) {
        int s[16];
#pragma unroll
        for (int j = 0; j < 16; ++j) s[j] = srcs_d[p + j];
        float a[16];
#pragma unroll
        for (int j = 0; j < 16; ++j) a[j] = ulo((unsigned)a16[(p + j) * 4 + h]);
        float v[16];
#pragma unroll
        for (int j = 0; j < 16; ++j) v[j] = b2f(cur[(size_t)s[j] * HD + lane]);
#pragma unroll
        for (int j = 0; j < 16; ++j) acc += a[j] * v[j];
    }
    if (p < re) {
        int cnt = re - p;
        int s[16];
#pragma unroll
        for (int j = 0; j < 16; ++j) s[j] = (j < cnt) ? srcs_d[p + j] : 0;
        float a[16];
#pragma unroll
        for (int j = 0; j < 16; ++j)
            a[j] = (j < cnt) ? ulo((unsigned)a16[(p + j) * 4 + h]) : 0.f;
        float v[16];
#pragma unroll
        for (int j = 0; j < 16; ++j)
            v[j] = (j < cnt) ? b2f(cur[(size_t)s[j] * HD + lane]) : 0.f;
#pragma unroll
        for (int j = 0; j < 16; ++j) acc += a[j] * v[j];
    }
    out[(size_t)n * HD + lane] = __float2bfloat16(acc);
}

// ---------------- feat_trans + hop attention + output (all-bf16 inputs) ----------------
__device__ __forceinline__ void unpack16(const bf16* p, float* x) {
    const uint4* q = (const uint4*)p;
    uint4 q0 = q[0], q1 = q[1];
    x[0] = ulo(q0.x);  x[1] = uhi(q0.x);  x[2] = ulo(q0.y);  x[3] = uhi(q0.y);
    x[4] = ulo(q0.z);  x[5] = uhi(q0.z);  x[6] = ulo(q0.w);  x[7] = uhi(q0.w);
    x[8] = ulo(q1.x);  x[9] = uhi(q1.x);  x[10] = ulo(q1.y); x[11] = uhi(q1.y);
    x[12] = ulo(q1.z); x[13] = uhi(q1.z); x[14] = ulo(q1.w); x[15] = uhi(q1.w);
}

__global__ void k_final(const bf16* __restrict__ ft16, const bf16* __restrict__ cur1,
                        const bf16* __restrict__ cur2, const bf16* __restrict__ cur3,
                        const float* __restrict__ hop_l, const float* __restrict__ hop_r,
                        const float* __restrict__ pos_emb, const float* __restrict__ scales,
                        const float* __restrict__ offs, const float* __restrict__ bias,
                        float* __restrict__ out) {
    int i = blockIdx.x * blockDim.x + threadIdx.x;  // i = n*3+h
    if (i >= N_NODES * HH) return;
    int h = i % HH;
    int n = i / HH;
    size_t sl = (size_t)n * HD + h * DD;
    float hk[4][DD];
#pragma unroll
    for (int k = 0; k < 4; ++k) {
        float x[DD];
        unpack16((k == 0) ? ft16 + sl : (k == 1) ? cur1 + sl : (k == 2) ? cur2 + sl
                                                                        : cur3 + sl, x);
        float m = 0.f;
#pragma unroll
        for (int d = 0; d < DD; ++d) m += x[d];
        m *= (1.f / DD);
        float v2 = 0.f;
#pragma unroll
        for (int d = 0; d < DD; ++d) {
            float c = x[d] - m;
            v2 += c * c;
        }
        v2 = v2 * (1.f / DD) + EPS_V;
        float rsq = rsqrtf(v2);
#pragma unroll
        for (int d = 0; d < DD; ++d) {
            hk[k][d] = (x[d] - m) * scales[k * HD + h * DD + d] * rsq +
                       offs[k * HD + h * DD + d] + pos_emb[h * 64 + k * DD + d];
        }
    }
    float al = 0.f;
#pragma unroll
    for (int d = 0; d < DD; ++d) al += hk[0][d] * hop_l[h * DD + d];
    float ar[3], mx = -1e30f;
#pragma unroll
    for (int k = 0; k < 3; ++k) {
        float s = 0.f;
#pragma unroll
        for (int d = 0; d < DD; ++d) s += hk[k + 1][d] * hop_r[h * DD + d];
        ar[k] = leaky(s + al);
        mx = fmaxf(mx, ar[k]);
    }
    float den = 0.f, wgt[3];
#pragma unroll
    for (int k = 0; k < 3; ++k) {
        wgt[k] = expf(ar[k] - mx);
        den += wgt[k];
    }
#pragma unroll
    for (int k = 0; k < 3; ++k) wgt[k] /= den;
#pragma unroll
    for (int d = 0; d < DD; ++d) {
        float o = hk[1][d] * wgt[0] + hk[2][d] * wgt[1] + hk[3][d] * wgt[2] +
                  bias[h * DD + d];
        out[i * DD + d] = o;
    }
}

// ---------------- workspace layout (4B-element offsets) ----------------
#define OFF_FT16   0u          // 2.4M slots (bf16 [N][48])
#define OFF_EL     2400000u    // 300k
#define OFF_ER     2700000u    // 300k
#define OFF_MSSRC  3000000u    // 600k (float2 x 300k)
#define OFF_BCNT   3600000u    // 1600 [memset]
#define OFF_BBASE  3601600u    // 800
#define OFF_ROWD   3602400u    // 100001
#define OFF_ROWS_  3702402u    // 100001
#define OFF_BKTD   3802404u    // 1.6M u32
#define OFF_BKTS   5402404u    // 1.6M u32
#define OFF_SRCSD  7002404u    // 1.6M
#define OFF_DSTSS  8602404u    // 1.6M
#define OFF_A16    10202404u   // 1.6M ushort4 = 3.2M slots ([E][4] bf16)
#define OFF_CUR1   13402404u   // 2.4M slots (bf16 [N][48])
#define OFF_CUR2   15802404u
#define OFF_CUR3   18202404u
#define WS_FLOATS  20602404u   // ~82.4 MB

extern "C" void kernel_launch(void* const* d_in, const int* in_sizes, int n_in,
                              void* d_out, int out_size, void* d_ws, size_t ws_size,
                              hipStream_t stream) {
    if (ws_size < (size_t)WS_FLOATS * 4) return;

    const float* feat   = (const float*)d_in[0];
    const int*   src    = (const int*)d_in[1];
    const int*   dst    = (const int*)d_in[2];
    const float* fc_W   = (const float*)d_in[3];
    const float* attn_l = (const float*)d_in[4];
    const float* attn_r = (const float*)d_in[5];
    const float* hop_l  = (const float*)d_in[6];
    const float* hop_r  = (const float*)d_in[7];
    const float* pos    = (const float*)d_in[8];
    const float* scal   = (const float*)d_in[9];
    const float* offs   = (const float*)d_in[10];
    const float* bias   = (const float*)d_in[11];
    float* out = (float*)d_out;

    float* ws = (float*)d_ws;
    bf16*     ft16    = (bf16*)(ws + OFF_FT16);
    float*    el      = ws + OFF_EL;
    float*    er      = ws + OFF_ER;
    float2*   mssrc   = (float2*)(ws + OFF_MSSRC);
    int*      bcnt_d  = (int*)(ws + OFF_BCNT);
    int*      bcnt_s  = bcnt_d + 400;
    int*      bfill_d = bcnt_d + 800;
    int*      bfill_s = bcnt_d + 1200;
    int*      bbase_d = (int*)(ws + OFF_BBASE);
    int*      bbase_s = bbase_d + 400;
    int*      rows_d  = (int*)(ws + OFF_ROWD);
    int*      rows_s  = (int*)(ws + OFF_ROWS_);
    unsigned* bkt_d   = (unsigned*)(ws + OFF_BKTD);
    unsigned* bkt_s   = (unsigned*)(ws + OFF_BKTS);
    int*      srcs_d  = (int*)(ws + OFF_SRCSD);
    int*      dsts_s  = (int*)(ws + OFF_DSTSS);
    ushort4*  a16     = (ushort4*)(ws + OFF_A16);
    bf16*     cur1    = (bf16*)(ws + OFF_CUR1);
    bf16*     cur2    = (bf16*)(ws + OFF_CUR2);
    bf16*     cur3    = (bf16*)(ws + OFF_CUR3);

    hipMemsetAsync(ws + OFF_BCNT, 0, 1600 * 4, stream);

    k_gemm<<<(N_NODES + 63) / 64, 256, 0, stream>>>(feat, fc_W, ft16);
    k_eler<<<(N_NODES * HH + 255) / 256, 256, 0, stream>>>(ft16, attn_l, attn_r, el, er);

    k_bhist<<<400, 256, 0, stream>>>((const int4*)src, (const int4*)dst, bcnt_s, bcnt_d);
    k_bscan<<<2, 512, 0, stream>>>(bcnt_d, bbase_d, bcnt_s, bbase_s, rows_d, rows_s);
    k_msplit<<<(N_EDGES + MS_T - 1) / MS_T, 256, 0, stream>>>(src, dst, bbase_d, bbase_s,
                                                              bfill_d, bfill_s, bkt_d, bkt_s);
    k_bfinal2<<<2 * NB, 256, 0, stream>>>(bkt_d, bkt_s, bbase_d, bbase_s,
                                          rows_d, rows_s, srcs_d, dsts_s);

    k_seg_src<<<(N_NODES + 3) / 4, 256, 0, stream>>>(dsts_s, rows_s, el, er, mssrc);
    k_seg_dst_attn<<<(N_NODES + 3) / 4, 256, 0, stream>>>(srcs_d, rows_d, el, er,
                                                          mssrc, a16);
    k_hop<<<(N_NODES + 3) / 4, 256, 0, stream>>>(ft16, (const unsigned short*)a16,
                                                 rows_d, srcs_d, cur1);
    k_hop<<<(N_NODES + 3) / 4, 256, 0, stream>>>(cur1, (const unsigned short*)a16,
                                                 rows_d, srcs_d, cur2);
    k_hop<<<(N_NODES + 3) / 4, 256, 0, stream>>>(cur2, (const unsigned short*)a16,
                                                 rows_d, srcs_d, cur3);
    k_final<<<(N_NODES * HH + 255) / 256, 256, 0, stream>>>(ft16, cur1, cur2, cur3, hop_l,
                                                            hop_r, pos, scal, offs, bias,
                                                            out);
}

// Round 15
// 452.579 us; speedup vs baseline: 1.6315x; 1.6315x over previous
//
#include <hip/hip_runtime.h>
#include <hip/hip_bf16.h>

typedef __hip_bfloat16 bf16;
typedef __attribute__((ext_vector_type(8))) short bf16x8;
typedef __attribute__((ext_vector_type(4))) float f32x4;

#define N_NODES 100000
#define N_EDGES 1600000
#define IN_F    128
#define HH      3      // heads
#define DD      16     // out feats per head
#define HD      48     // HH*DD
#define NEG_SLOPE 0.2f
#define EPS_V   1e-9f

#define NB      391    // ceil(N_NODES / 256) buckets
#define BW_SH   8      // bucket = node >> 8 (256 nodes per bucket)
#define MS_T    8192   // edges per multisplit workgroup

__device__ __forceinline__ float leaky(float x) { return x >= 0.f ? x : NEG_SLOPE * x; }
__device__ __forceinline__ float b2f(bf16 x) { return __bfloat162float(x); }
__device__ __forceinline__ unsigned short bfbits(float x) {
    return __builtin_bit_cast(unsigned short, __float2bfloat16(x));
}
__device__ __forceinline__ unsigned pkbf(float a, float b) {
    return (unsigned)bfbits(a) | ((unsigned)bfbits(b) << 16);
}
__device__ __forceinline__ float ulo(unsigned u) { return __uint_as_float(u << 16); }
__device__ __forceinline__ float uhi(unsigned u) { return __uint_as_float(u & 0xffff0000u); }

// ------- GEMM via MFMA: 64 rows/block (4 waves x 16-row tile), bf16 LDS staging -------
#define FS_LD 136   // padded row length in bf16 elems
__global__ __launch_bounds__(256) void k_gemm(const float* __restrict__ feat,
                                              const float* __restrict__ W,
                                              bf16* __restrict__ ft16) {
    __shared__ unsigned short Fs[64][FS_LD];   // ~17.4 KB
    int t = threadIdx.x;
    int row0 = blockIdx.x * 64;
    int lane = t & 63, wv = t >> 6;

    int bc = lane & 15, bk0 = (lane >> 4) * 8;
    bf16x8 bfrag[4][3];
#pragma unroll
    for (int kk = 0; kk < 4; ++kk)
#pragma unroll
        for (int nt = 0; nt < 3; ++nt)
#pragma unroll
            for (int j = 0; j < 8; ++j)
                bfrag[kk][nt][j] =
                    (short)bfbits(W[(kk * 32 + bk0 + j) * HD + nt * 16 + bc]);

    for (int i = t; i < 64 * 32; i += 256) {
        int r = i >> 5, c4 = i & 31;
        int gr = row0 + r;
        float4 v = make_float4(0.f, 0.f, 0.f, 0.f);
        if (gr < N_NODES) v = ((const float4*)feat)[(size_t)gr * 32 + c4];
        *(uint2*)&Fs[r][c4 * 4] = make_uint2(pkbf(v.x, v.y), pkbf(v.z, v.w));
    }
    __syncthreads();

    int ar = lane & 15, ak0 = (lane >> 4) * 8;
    const unsigned short* arow = &Fs[wv * 16 + ar][0];
    f32x4 acc0 = {0.f, 0.f, 0.f, 0.f};
    f32x4 acc1 = {0.f, 0.f, 0.f, 0.f};
    f32x4 acc2 = {0.f, 0.f, 0.f, 0.f};
#pragma unroll
    for (int kk = 0; kk < 4; ++kk) {
        bf16x8 af = *(const bf16x8*)&arow[kk * 32 + ak0];
        acc0 = __builtin_amdgcn_mfma_f32_16x16x32_bf16(af, bfrag[kk][0], acc0, 0, 0, 0);
        acc1 = __builtin_amdgcn_mfma_f32_16x16x32_bf16(af, bfrag[kk][1], acc1, 0, 0, 0);
        acc2 = __builtin_amdgcn_mfma_f32_16x16x32_bf16(af, bfrag[kk][2], acc2, 0, 0, 0);
    }
    int orow = row0 + wv * 16 + (lane >> 4) * 4;
    int ocol = lane & 15;
#pragma unroll
    for (int r = 0; r < 4; ++r) {
        int gr = orow + r;
        if (gr < N_NODES) {
            bf16* o = ft16 + (size_t)gr * HD + ocol;
            o[0]  = __float2bfloat16(acc0[r]);
            o[16] = __float2bfloat16(acc1[r]);
            o[32] = __float2bfloat16(acc2[r]);
        }
    }
}

// ---------------- el/er from bf16 ft ----------------
__global__ void k_eler(const bf16* __restrict__ ft16, const float* __restrict__ attn_l,
                       const float* __restrict__ attn_r, float* __restrict__ el,
                       float* __restrict__ er) {
    int i = blockIdx.x * blockDim.x + threadIdx.x;  // n*3+h
    if (i >= N_NODES * HH) return;
    int h = i % HH;
    const uint4* p = (const uint4*)(ft16 + (size_t)i * DD);
    uint4 q0 = p[0], q1 = p[1];
    float x[DD];
    x[0] = ulo(q0.x);  x[1] = uhi(q0.x);  x[2] = ulo(q0.y);  x[3] = uhi(q0.y);
    x[4] = ulo(q0.z);  x[5] = uhi(q0.z);  x[6] = ulo(q0.w);  x[7] = uhi(q0.w);
    x[8] = ulo(q1.x);  x[9] = uhi(q1.x);  x[10] = ulo(q1.y); x[11] = uhi(q1.y);
    x[12] = ulo(q1.z); x[13] = uhi(q1.z); x[14] = ulo(q1.w); x[15] = uhi(q1.w);
    float sl = 0.f, sr = 0.f;
#pragma unroll
    for (int d = 0; d < DD; ++d) {
        sl += x[d] * attn_l[h * DD + d];
        sr += x[d] * attn_r[h * DD + d];
    }
    el[i] = sl;
    er[i] = sr;
}

// ---------------- K1: per-bucket histograms (LDS-privatized, int4 loads) -------------
__global__ __launch_bounds__(256) void k_bhist(const int4* __restrict__ src4,
                                               const int4* __restrict__ dst4,
                                               int* __restrict__ bcnt_s,
                                               int* __restrict__ bcnt_d) {
    __shared__ int ls[NB], ld_[NB];
    int t = threadIdx.x;
    for (int i = t; i < NB; i += 256) { ls[i] = 0; ld_[i] = 0; }
    __syncthreads();
    const int NE4 = N_EDGES / 4;
    for (int e = blockIdx.x * 256 + t; e < NE4; e += gridDim.x * 256) {
        int4 d = dst4[e];
        atomicAdd(&ld_[d.x >> BW_SH], 1);
        atomicAdd(&ld_[d.y >> BW_SH], 1);
        atomicAdd(&ld_[d.z >> BW_SH], 1);
        atomicAdd(&ld_[d.w >> BW_SH], 1);
        int4 s = src4[e];
        atomicAdd(&ls[s.x >> BW_SH], 1);
        atomicAdd(&ls[s.y >> BW_SH], 1);
        atomicAdd(&ls[s.z >> BW_SH], 1);
        atomicAdd(&ls[s.w >> BW_SH], 1);
    }
    __syncthreads();
    for (int i = t; i < NB; i += 256) {
        if (ld_[i]) atomicAdd(&bcnt_d[i], ld_[i]);
        if (ls[i]) atomicAdd(&bcnt_s[i], ls[i]);
    }
}

// ---------------- K2: scan bucket counts -> bucket bases (+ sentinels) -------------
__global__ __launch_bounds__(512) void k_bscan(const int* __restrict__ bcnt_d,
                                               int* __restrict__ bbase_d,
                                               const int* __restrict__ bcnt_s,
                                               int* __restrict__ bbase_s,
                                               int* __restrict__ rows_d,
                                               int* __restrict__ rows_s) {
    __shared__ int buf[512];
    const int* c = blockIdx.x ? bcnt_s : bcnt_d;
    int* o = blockIdx.x ? bbase_s : bbase_d;
    int t = threadIdx.x;
    int v = (t < NB) ? c[t] : 0;
    buf[t] = v;
    __syncthreads();
    for (int off = 1; off < 512; off <<= 1) {
        int u = (t >= off) ? buf[t - off] : 0;
        __syncthreads();
        buf[t] += u;
        __syncthreads();
    }
    if (t < NB) o[t] = buf[t] - v;      // exclusive
    if (t == NB - 1) o[NB] = buf[t];    // == N_EDGES
    if (t == 0) {
        if (blockIdx.x) rows_s[N_NODES] = N_EDGES;
        else            rows_d[N_NODES] = N_EDGES;
    }
}

// ---------------- K3: multisplit — bucket edges for both directions ----------------
__global__ __launch_bounds__(256) void k_msplit(const int* __restrict__ src,
                                                const int* __restrict__ dst,
                                                const int* __restrict__ bbase_d,
                                                const int* __restrict__ bbase_s,
                                                int* __restrict__ bfill_d,
                                                int* __restrict__ bfill_s,
                                                unsigned* __restrict__ bkt_d,
                                                unsigned* __restrict__ bkt_s) {
    __shared__ int lcD[NB], lcS[NB], wbD[NB], wbS[NB], rkD[NB], rkS[NB];
    int t = threadIdx.x;
    int e0 = blockIdx.x * MS_T;
    int e1 = min(e0 + MS_T, N_EDGES);
    for (int i = t; i < NB; i += 256) { lcD[i] = 0; lcS[i] = 0; rkD[i] = 0; rkS[i] = 0; }
    __syncthreads();
    for (int e = e0 + t; e < e1; e += 256) {
        atomicAdd(&lcD[dst[e] >> BW_SH], 1);
        atomicAdd(&lcS[src[e] >> BW_SH], 1);
    }
    __syncthreads();
    for (int i = t; i < NB; i += 256) {
        wbD[i] = bbase_d[i] + (lcD[i] ? atomicAdd(&bfill_d[i], lcD[i]) : 0);
        wbS[i] = bbase_s[i] + (lcS[i] ? atomicAdd(&bfill_s[i], lcS[i]) : 0);
    }
    __syncthreads();
    for (int e = e0 + t; e < e1; e += 256) {
        int s = src[e], d = dst[e];
        int bd = d >> BW_SH, bs = s >> BW_SH;
        int rd = atomicAdd(&rkD[bd], 1);
        int rs = atomicAdd(&rkS[bs], 1);
        bkt_d[wbD[bd] + rd] = (unsigned)s | ((unsigned)(d & 255) << 17);
        bkt_s[wbS[bs] + rs] = (unsigned)d | ((unsigned)(s & 255) << 17);
    }
}

// ------- K4: per-bucket CSR finalize, both directions in one launch (grid 2*NB) ------
__global__ __launch_bounds__(256) void k_bfinal2(const unsigned* __restrict__ bkt_d,
                                                 const unsigned* __restrict__ bkt_s,
                                                 const int* __restrict__ bbase_d,
                                                 const int* __restrict__ bbase_s,
                                                 int* __restrict__ rows_d,
                                                 int* __restrict__ rows_s,
                                                 int* __restrict__ srcs_d,
                                                 int* __restrict__ dsts_s) {
    __shared__ int cnt[256], pre[256], rnk[256], wsum[4];
    int bb = blockIdx.x, t = threadIdx.x;
    bool isD = bb < NB;
    int b = isD ? bb : bb - NB;
    const unsigned* bkt = isD ? bkt_d : bkt_s;
    const int* bbase = isD ? bbase_d : bbase_s;
    int* rows = isD ? rows_d : rows_s;
    int* outarr = isD ? srcs_d : dsts_s;
    int base = bbase[b], end = bbase[b + 1];
    cnt[t] = 0; rnk[t] = 0;
    __syncthreads();
    for (int i = base + t; i < end; i += 256)
        atomicAdd(&cnt[(bkt[i] >> 17) & 255], 1);
    __syncthreads();
    int lane = t & 63, w = t >> 6;
    int v = cnt[t];
    int sc = v;
#pragma unroll
    for (int off = 1; off < 64; off <<= 1) {
        int u = __shfl_up(sc, off, 64);
        if (lane >= off) sc += u;
    }
    if (lane == 63) wsum[w] = sc;
    __syncthreads();
    int wpre = 0;
    for (int j = 0; j < w; ++j) wpre += wsum[j];
    int excl = wpre + sc - v;
    pre[t] = excl;
    int n = (b << BW_SH) + t;
    if (n < N_NODES) rows[n] = base + excl;
    __syncthreads();
    for (int i = base + t; i < end; i += 256) {
        unsigned u = bkt[i];
        int loc = (u >> 17) & 255;
        int r = atomicAdd(&rnk[loc], 1);
        outarr[base + pre[loc] + r] = (int)(u & 0x1FFFFu);
    }
}

// -------- src-side segment softmax stats: per-node (max, sum) only ----------
__global__ __launch_bounds__(256) void k_seg_src(const int* __restrict__ dsts_s,
                                                 const int* __restrict__ rows_s,
                                                 const float* __restrict__ el,
                                                 const float* __restrict__ er,
                                                 float2* __restrict__ mssrc) {
    int wid = threadIdx.x >> 6, lane = threadIdx.x & 63;
    int n = blockIdx.x * 4 + wid;
    if (n >= N_NODES) return;
    int rs = rows_s[n], re = rows_s[n + 1];
    if (rs >= re) return;
    float el0 = el[n * 3 + 0], el1 = el[n * 3 + 1], el2 = el[n * 3 + 2];
    bool single = (re - rs) <= 64;
    float m0 = -INFINITY, m1 = -INFINITY, m2 = -INFINITY;
    float c0 = -INFINITY, c1 = -INFINITY, c2 = -INFINITY;
    for (int p0 = rs; p0 < re; p0 += 64) {
        int p = p0 + lane;
        bool act = p < re;
        int d = act ? dsts_s[p] : 0;
        float t0 = act ? leaky(el0 + er[d * 3 + 0]) : -INFINITY;
        float t1 = act ? leaky(el1 + er[d * 3 + 1]) : -INFINITY;
        float t2 = act ? leaky(el2 + er[d * 3 + 2]) : -INFINITY;
        if (single) { c0 = t0; c1 = t1; c2 = t2; }
        m0 = fmaxf(m0, t0); m1 = fmaxf(m1, t1); m2 = fmaxf(m2, t2);
    }
#pragma unroll
    for (int off = 1; off < 64; off <<= 1) {
        m0 = fmaxf(m0, __shfl_xor(m0, off));
        m1 = fmaxf(m1, __shfl_xor(m1, off));
        m2 = fmaxf(m2, __shfl_xor(m2, off));
    }
    float s0 = 0, s1 = 0, s2 = 0;
    if (single) {
        bool act = (rs + lane) < re;
        s0 = act ? expf(c0 - m0) : 0.f;
        s1 = act ? expf(c1 - m1) : 0.f;
        s2 = act ? expf(c2 - m2) : 0.f;
    } else {
        for (int p0 = rs; p0 < re; p0 += 64) {
            int p = p0 + lane;
            if (p < re) {
                int d = dsts_s[p];
                s0 += expf(leaky(el0 + er[d * 3 + 0]) - m0);
                s1 += expf(leaky(el1 + er[d * 3 + 1]) - m1);
                s2 += expf(leaky(el2 + er[d * 3 + 2]) - m2);
            }
        }
    }
#pragma unroll
    for (int off = 1; off < 64; off <<= 1) {
        s0 += __shfl_xor(s0, off);
        s1 += __shfl_xor(s1, off);
        s2 += __shfl_xor(s2, off);
    }
    if (lane == 0) {
        mssrc[n * 3 + 0] = make_float2(m0, s0);
        mssrc[n * 3 + 1] = make_float2(m1, s1);
        mssrc[n * 3 + 2] = make_float2(m2, s2);
    }
}

// ---- dst-side stats + fused symmetric attention; a stored f32 interleaved [E][3] ----
__global__ __launch_bounds__(256) void k_seg_dst_attn(const int* __restrict__ srcs_d,
                                                      const int* __restrict__ rows_d,
                                                      const float* __restrict__ el,
                                                      const float* __restrict__ er,
                                                      const float2* __restrict__ mssrc,
                                                      float* __restrict__ a_sorted) {
    int wid = threadIdx.x >> 6, lane = threadIdx.x & 63;
    int n = blockIdx.x * 4 + wid;
    if (n >= N_NODES) return;
    int rs = rows_d[n], re = rows_d[n + 1];
    if (rs >= re) return;
    float er0 = er[n * 3 + 0], er1 = er[n * 3 + 1], er2 = er[n * 3 + 2];
    bool single = (re - rs) <= 64;
    float m0 = -INFINITY, m1 = -INFINITY, m2 = -INFINITY;
    float c0 = -INFINITY, c1 = -INFINITY, c2 = -INFINITY;
    int scache = 0;
    for (int p0 = rs; p0 < re; p0 += 64) {
        int p = p0 + lane;
        bool act = p < re;
        int s = act ? srcs_d[p] : 0;
        if (single) scache = s;
        float t0 = act ? leaky(el[s * 3 + 0] + er0) : -INFINITY;
        float t1 = act ? leaky(el[s * 3 + 1] + er1) : -INFINITY;
        float t2 = act ? leaky(el[s * 3 + 2] + er2) : -INFINITY;
        if (single) { c0 = t0; c1 = t1; c2 = t2; }
        m0 = fmaxf(m0, t0); m1 = fmaxf(m1, t1); m2 = fmaxf(m2, t2);
    }
#pragma unroll
    for (int off = 1; off < 64; off <<= 1) {
        m0 = fmaxf(m0, __shfl_xor(m0, off));
        m1 = fmaxf(m1, __shfl_xor(m1, off));
        m2 = fmaxf(m2, __shfl_xor(m2, off));
    }
    float s0 = 0, s1 = 0, s2 = 0;
    if (single) {
        bool act = (rs + lane) < re;
        s0 = act ? expf(c0 - m0) : 0.f;
        s1 = act ? expf(c1 - m1) : 0.f;
        s2 = act ? expf(c2 - m2) : 0.f;
    } else {
        for (int p0 = rs; p0 < re; p0 += 64) {
            int p = p0 + lane;
            if (p < re) {
                int s = srcs_d[p];
                s0 += expf(leaky(el[s * 3 + 0] + er0) - m0);
                s1 += expf(leaky(el[s * 3 + 1] + er1) - m1);
                s2 += expf(leaky(el[s * 3 + 2] + er2) - m2);
            }
        }
    }
#pragma unroll
    for (int off = 1; off < 64; off <<= 1) {
        s0 += __shfl_xor(s0, off);
        s1 += __shfl_xor(s1, off);
        s2 += __shfl_xor(s2, off);
    }
    float i0 = 1.f / s0, i1 = 1.f / s1, i2 = 1.f / s2;
    for (int p0 = rs; p0 < re; p0 += 64) {
        int p = p0 + lane;
        if (p >= re) break;
        int s = single ? scache : srcs_d[p];
        float t0, t1, t2;
        if (single) { t0 = c0; t1 = c1; t2 = c2; }
        else {
            t0 = leaky(el[s * 3 + 0] + er0);
            t1 = leaky(el[s * 3 + 1] + er1);
            t2 = leaky(el[s * 3 + 2] + er2);
        }
        float2 a0 = mssrc[s * 3 + 0], a1 = mssrc[s * 3 + 1], a2 = mssrc[s * 3 + 2];
        float d0 = fmaxf(expf(t0 - m0) * i0, EPS_V);
        float d1 = fmaxf(expf(t1 - m1) * i1, EPS_V);
        float d2 = fmaxf(expf(t2 - m2) * i2, EPS_V);
        float u0 = fmaxf(expf(t0 - a0.x) / a0.y, EPS_V);
        float u1 = fmaxf(expf(t1 - a1.x) / a1.y, EPS_V);
        float u2 = fmaxf(expf(t2 - a2.x) / a2.y, EPS_V);
        a_sorted[p * 3 + 0] = sqrtf(d0 * u0);
        a_sorted[p * 3 + 1] = sqrtf(d1 * u1);
        a_sorted[p * 3 + 2] = sqrtf(d2 * u2);
    }
}

// ------- hop: wave per node, 48 lanes, 96 B bf16 rows, f32 a [E][3], 8-deep ---------
__global__ __launch_bounds__(256) void k_hop(const bf16* __restrict__ cur,
                                             const float* __restrict__ a_sorted,
                                             const int* __restrict__ rows_d,
                                             const int* __restrict__ srcs_d,
                                             bf16* __restrict__ out) {
    int wid = threadIdx.x >> 6, lane = threadIdx.x & 63;
    int n = blockIdx.x * 4 + wid;
    if (n >= N_NODES) return;
    if (lane >= HD) return;
    int h = lane >> 4;
    int rs = rows_d[n], re = rows_d[n + 1];
    float acc = 0.f;
    int p = rs;
    for (; p + 8 <= re; p += 8) {
        int s[8];
#pragma unroll
        for (int j = 0; j < 8; ++j) s[j] = srcs_d[p + j];
        float a[8];
#pragma unroll
        for (int j = 0; j < 8; ++j) a[j] = a_sorted[(p + j) * HH + h];
        float v[8];
#pragma unroll
        for (int j = 0; j < 8; ++j) v[j] = b2f(cur[(size_t)s[j] * HD + lane]);
#pragma unroll
        for (int j = 0; j < 8; ++j) acc += a[j] * v[j];
    }
    if (p < re) {
        int cnt = re - p;
        int s[8];
#pragma unroll
        for (int j = 0; j < 8; ++j) s[j] = (j < cnt) ? srcs_d[p + j] : 0;
        float a[8];
#pragma unroll
        for (int j = 0; j < 8; ++j) a[j] = (j < cnt) ? a_sorted[(p + j) * HH + h] : 0.f;
        float v[8];
#pragma unroll
        for (int j = 0; j < 8; ++j) v[j] = (j < cnt) ? b2f(cur[(size_t)s[j] * HD + lane]) : 0.f;
#pragma unroll
        for (int j = 0; j < 8; ++j) acc += a[j] * v[j];
    }
    out[(size_t)n * HD + lane] = __float2bfloat16(acc);
}

// ---------------- feat_trans + hop attention + output (all-bf16 inputs) ----------------
__device__ __forceinline__ void unpack16(const bf16* p, float* x) {
    const uint4* q = (const uint4*)p;
    uint4 q0 = q[0], q1 = q[1];
    x[0] = ulo(q0.x);  x[1] = uhi(q0.x);  x[2] = ulo(q0.y);  x[3] = uhi(q0.y);
    x[4] = ulo(q0.z);  x[5] = uhi(q0.z);  x[6] = ulo(q0.w);  x[7] = uhi(q0.w);
    x[8] = ulo(q1.x);  x[9] = uhi(q1.x);  x[10] = ulo(q1.y); x[11] = uhi(q1.y);
    x[12] = ulo(q1.z); x[13] = uhi(q1.z); x[14] = ulo(q1.w); x[15] = uhi(q1.w);
}

__global__ void k_final(const bf16* __restrict__ ft16, const bf16* __restrict__ cur1,
                        const bf16* __restrict__ cur2, const bf16* __restrict__ cur3,
                        const float* __restrict__ hop_l, const float* __restrict__ hop_r,
                        const float* __restrict__ pos_emb, const float* __restrict__ scales,
                        const float* __restrict__ offs, const float* __restrict__ bias,
                        float* __restrict__ out) {
    int i = blockIdx.x * blockDim.x + threadIdx.x;  // i = n*3+h
    if (i >= N_NODES * HH) return;
    int h = i % HH;
    int n = i / HH;
    size_t sl = (size_t)n * HD + h * DD;
    float hk[4][DD];
#pragma unroll
    for (int k = 0; k < 4; ++k) {
        float x[DD];
        unpack16((k == 0) ? ft16 + sl : (k == 1) ? cur1 + sl : (k == 2) ? cur2 + sl
                                                                        : cur3 + sl, x);
        float m = 0.f;
#pragma unroll
        for (int d = 0; d < DD; ++d) m += x[d];
        m *= (1.f / DD);
        float v2 = 0.f;
#pragma unroll
        for (int d = 0; d < DD; ++d) {
            float c = x[d] - m;
            v2 += c * c;
        }
        v2 = v2 * (1.f / DD) + EPS_V;
        float rsq = rsqrtf(v2);
#pragma unroll
        for (int d = 0; d < DD; ++d) {
            hk[k][d] = (x[d] - m) * scales[k * HD + h * DD + d] * rsq +
                       offs[k * HD + h * DD + d] + pos_emb[h * 64 + k * DD + d];
        }
    }
    float al = 0.f;
#pragma unroll
    for (int d = 0; d < DD; ++d) al += hk[0][d] * hop_l[h * DD + d];
    float ar[3], mx = -1e30f;
#pragma unroll
    for (int k = 0; k < 3; ++k) {
        float s = 0.f;
#pragma unroll
        for (int d = 0; d < DD; ++d) s += hk[k + 1][d] * hop_r[h * DD + d];
        ar[k] = leaky(s + al);
        mx = fmaxf(mx, ar[k]);
    }
    float den = 0.f, wgt[3];
#pragma unroll
    for (int k = 0; k < 3; ++k) {
        wgt[k] = expf(ar[k] - mx);
        den += wgt[k];
    }
#pragma unroll
    for (int k = 0; k < 3; ++k) wgt[k] /= den;
#pragma unroll
    for (int d = 0; d < DD; ++d) {
        float o = hk[1][d] * wgt[0] + hk[2][d] * wgt[1] + hk[3][d] * wgt[2] +
                  bias[h * DD + d];
        out[i * DD + d] = o;
    }
}

// ---------------- workspace layout (4B-element offsets) ----------------
#define OFF_FT16   0u          // 2.4M slots (bf16 [N][48])
#define OFF_EL     2400000u    // 300k
#define OFF_ER     2700000u    // 300k
#define OFF_MSSRC  3000000u    // 600k (float2 x 300k)
#define OFF_BCNT   3600000u    // 1600 [memset]
#define OFF_BBASE  3601600u    // 800
#define OFF_ROWD   3602400u    // 100001
#define OFF_ROWS_  3702402u    // 100001
#define OFF_BKTD   3802404u    // 1.6M u32
#define OFF_BKTS   5402404u    // 1.6M u32
#define OFF_SRCSD  7002404u    // 1.6M
#define OFF_DSTSS  8602404u    // 1.6M
#define OFF_ASORT  10202404u   // 4.8M f32 ([E][3] interleaved)
#define OFF_CUR1   15002404u   // 2.4M slots (bf16 [N][48])
#define OFF_CUR2   17402404u
#define OFF_CUR3   19802404u
#define WS_FLOATS  22202404u   // ~88.8 MB

extern "C" void kernel_launch(void* const* d_in, const int* in_sizes, int n_in,
                              void* d_out, int out_size, void* d_ws, size_t ws_size,
                              hipStream_t stream) {
    if (ws_size < (size_t)WS_FLOATS * 4) return;

    const float* feat   = (const float*)d_in[0];
    const int*   src    = (const int*)d_in[1];
    const int*   dst    = (const int*)d_in[2];
    const float* fc_W   = (const float*)d_in[3];
    const float* attn_l = (const float*)d_in[4];
    const float* attn_r = (const float*)d_in[5];
    const float* hop_l  = (const float*)d_in[6];
    const float* hop_r  = (const float*)d_in[7];
    const float* pos    = (const float*)d_in[8];
    const float* scal   = (const float*)d_in[9];
    const float* offs   = (const float*)d_in[10];
    const float* bias   = (const float*)d_in[11];
    float* out = (float*)d_out;

    float* ws = (float*)d_ws;
    bf16*     ft16    = (bf16*)(ws + OFF_FT16);
    float*    el      = ws + OFF_EL;
    float*    er      = ws + OFF_ER;
    float2*   mssrc   = (float2*)(ws + OFF_MSSRC);
    int*      bcnt_d  = (int*)(ws + OFF_BCNT);
    int*      bcnt_s  = bcnt_d + 400;
    int*      bfill_d = bcnt_d + 800;
    int*      bfill_s = bcnt_d + 1200;
    int*      bbase_d = (int*)(ws + OFF_BBASE);
    int*      bbase_s = bbase_d + 400;
    int*      rows_d  = (int*)(ws + OFF_ROWD);
    int*      rows_s  = (int*)(ws + OFF_ROWS_);
    unsigned* bkt_d   = (unsigned*)(ws + OFF_BKTD);
    unsigned* bkt_s   = (unsigned*)(ws + OFF_BKTS);
    int*      srcs_d  = (int*)(ws + OFF_SRCSD);
    int*      dsts_s  = (int*)(ws + OFF_DSTSS);
    float*    a_sorted= ws + OFF_ASORT;
    bf16*     cur1    = (bf16*)(ws + OFF_CUR1);
    bf16*     cur2    = (bf16*)(ws + OFF_CUR2);
    bf16*     cur3    = (bf16*)(ws + OFF_CUR3);

    hipMemsetAsync(ws + OFF_BCNT, 0, 1600 * 4, stream);

    k_gemm<<<(N_NODES + 63) / 64, 256, 0, stream>>>(feat, fc_W, ft16);
    k_eler<<<(N_NODES * HH + 255) / 256, 256, 0, stream>>>(ft16, attn_l, attn_r, el, er);

    k_bhist<<<400, 256, 0, stream>>>((const int4*)src, (const int4*)dst, bcnt_s, bcnt_d);
    k_bscan<<<2, 512, 0, stream>>>(bcnt_d, bbase_d, bcnt_s, bbase_s, rows_d, rows_s);
    k_msplit<<<(N_EDGES + MS_T - 1) / MS_T, 256, 0, stream>>>(src, dst, bbase_d, bbase_s,
                                                              bfill_d, bfill_s, bkt_d, bkt_s);
    k_bfinal2<<<2 * NB, 256, 0, stream>>>(bkt_d, bkt_s, bbase_d, bbase_s,
                                          rows_d, rows_s, srcs_d, dsts_s);

    k_seg_src<<<(N_NODES + 3) / 4, 256, 0, stream>>>(dsts_s, rows_s, el, er, mssrc);
    k_seg_dst_attn<<<(N_NODES + 3) / 4, 256, 0, stream>>>(srcs_d, rows_d, el, er,
                                                          mssrc, a_sorted);
    k_hop<<<(N_NODES + 3) / 4, 256, 0, stream>>>(ft16, a_sorted, rows_d, srcs_d, cur1);
    k_hop<<<(N_NODES + 3) / 4, 256, 0, stream>>>(cur1, a_sorted, rows_d, srcs_d, cur2);
    k_hop<<<(N_NODES + 3) / 4, 256, 0, stream>>>(cur2, a_sorted, rows_d, srcs_d, cur3);
    k_final<<<(N_NODES * HH + 255) / 256, 256, 0, stream>>>(ft16, cur1, cur2, cur3, hop_l,
                                                            hop_r, pos, scal, offs, bias,
                                                            out);
}